// Round 7
// baseline (758.599 us; speedup 1.0000x reference)
//
#include <hip/hip_runtime.h>
#include <math.h>

#define CCH    512
#define HWN    4096
#define NPIX   65536
#define OC3    1536
#define QSCALE 0.125f
#define LN_EPS 1e-5f

typedef _Float16 h16;
typedef h16  f16x8 __attribute__((ext_vector_type(8)));
typedef float f32x4 __attribute__((ext_vector_type(4)));

__device__ __forceinline__ float waveReduceSum(float v) {
#pragma unroll
    for (int off = 32; off; off >>= 1) v += __shfl_xor(v, off);
    return v;
}
__device__ __forceinline__ float waveReduceMax(float v) {
#pragma unroll
    for (int off = 32; off; off >>= 1) v = fmaxf(v, __shfl_xor(v, off));
    return v;
}

__device__ __forceinline__ void gl_lds16(const void* g, void* l) {
    __builtin_amdgcn_global_load_lds((const __attribute__((address_space(1))) void*)g,
                                     (__attribute__((address_space(3))) void*)l, 16, 0, 0);
}

// ---------------------------------------------------------------------------
// merged weight prep: o<1536 -> wg (w_qkv*g_ln, x64, hi/lo) + row-sum s;
//                     o>=1536 -> wo (w_out, x64, hi/lo)
__global__ __launch_bounds__(64) void prep_w(const float* __restrict__ w_qkv,
                                             const float* __restrict__ g_ln,
                                             const float* __restrict__ w_out,
                                             h16* __restrict__ wg_h, h16* __restrict__ wg_l,
                                             float* __restrict__ s,
                                             h16* __restrict__ wo_h, h16* __restrict__ wo_l) {
    const int o = blockIdx.x, lane = threadIdx.x;
    if (o < OC3) {
        float sum = 0.f;
#pragma unroll
        for (int j = 0; j < 8; ++j) {
            const int c = lane + j * 64;
            const float w = w_qkv[(size_t)o * CCH + c] * g_ln[c];
            const float ws = w * 64.f;
            const h16 hi = (h16)ws;
            wg_h[(size_t)o * CCH + c] = hi;
            wg_l[(size_t)o * CCH + c] = (h16)(ws - (float)hi);
            sum += w;
        }
        sum = waveReduceSum(sum);
        if (lane == 0) s[o] = sum;
    } else {
        const int r = o - OC3;
#pragma unroll
        for (int j = 0; j < 8; ++j) {
            const int c = lane + j * 64;
            const float ws = w_out[(size_t)r * CCH + c] * 64.f;
            const h16 hi = (h16)ws;
            wo_h[(size_t)r * CCH + c] = hi;
            wo_l[(size_t)r * CCH + c] = (h16)(ws - (float)hi);
        }
    }
}

// ---------------------------------------------------------------------------
// QKV GEMM with fused x-transpose + LN-stats.
// 128x128 MFMA tile, fp16 split-2 (A hi/lo x B), K=512, 256 threads.
// A = wg (x64 scaled, fp16 hi/lo, K-contig) via global_load_lds.
// B = x fp32 [b][ch][px], reg-staged: coalesced loads -> fp16 cvt -> swizzled
//     ds_write (transpose). LN s1/s2 accumulated during staging; mean/rstd
//     computed in-block; epilogue: out fp16 = rstd*(acc/64 - mean*s[o]).
__global__ __launch_bounds__(256) void qkv_gemm(const h16* __restrict__ Ahg,
                                                const h16* __restrict__ Alg,
                                                const float* __restrict__ xg,
                                                const float* __restrict__ sv,
                                                h16* __restrict__ qout) {
    __shared__ __align__(16) h16 Ah[4096], Al[4096], Bh[4096];
    const int tid = threadIdx.x;
    const int om = blockIdx.x * 128;
    const int by0 = blockIdx.y;
    const int by  = (by0 & 7) * 64 + (by0 >> 3);   // bijective XCD chunking (512%8==0)
    const int p0  = by * 128;
    const int bb  = p0 >> 12, hw0 = p0 & 4095;

    // A staging map (global_load_lds, linear dest):
    const int srow = tid >> 2;
    const int skh  = ((tid & 3) ^ (srow & 3)) * 8;
    const size_t a0 = (size_t)(om + srow) * CCH + skh;
    const int wofs = (tid >> 6) * 512;

    // B staging map (reg-staged from x): thread -> pixel bpx, slots {bslot, bslot+2}
    const int bpx   = tid >> 1;      // 0..127
    const int bslot = tid & 1;       // ch groups (kc + bslot*8) and (+16)
    const float* xbase = xg + (size_t)bb * CCH * HWN + hw0 + bpx;

    // MFMA fragment map:
    const int lane = tid & 63;
    const int wv = tid >> 6;
    const int wm = (wv >> 1) * 64, wn = (wv & 1) * 64;
    const int lr = lane & 15, kg = lane >> 4;
    const int swz = (kg ^ (lr & 3)) * 8;

    f32x4 acc[4][4];
#pragma unroll
    for (int i = 0; i < 4; ++i)
#pragma unroll
        for (int j = 0; j < 4; ++j) acc[i][j] = {0.f, 0.f, 0.f, 0.f};

    float Lb[16];
    float s1t = 0.f, s2t = 0.f;

#define AGLOAD(KC)                                               \
    do {                                                         \
        gl_lds16(Ahg + a0 + (KC), Ah + wofs);                    \
        gl_lds16(Ahg + a0 + (KC) + 64 * CCH, Ah + 2048 + wofs);  \
        gl_lds16(Alg + a0 + (KC), Al + wofs);                    \
        gl_lds16(Alg + a0 + (KC) + 64 * CCH, Al + 2048 + wofs);  \
    } while (0)

#define LOADB(KC)                                                \
    do {                                                         \
        const size_t c0 = (size_t)((KC) + bslot * 8) * HWN;      \
        _Pragma("unroll")                                        \
        for (int c = 0; c < 8; ++c) {                            \
            Lb[c]     = xbase[c0 + (size_t)c * HWN];             \
            Lb[c + 8] = xbase[c0 + (size_t)(c + 16) * HWN];      \
        }                                                        \
    } while (0)

#define CVTB()                                                   \
    do {                                                         \
        f16x8 v0, v1;                                            \
        _Pragma("unroll")                                        \
        for (int c = 0; c < 8; ++c) {                            \
            const float va = Lb[c], vb = Lb[c + 8];              \
            s1t += va + vb;                                      \
            s2t += va * va + vb * vb;                            \
            v0[c] = (h16)va;                                     \
            v1[c] = (h16)vb;                                     \
        }                                                        \
        const int sw0 = ((bslot)     ^ (bpx & 3)) * 8;           \
        const int sw1 = ((bslot + 2) ^ (bpx & 3)) * 8;           \
        *(f16x8*)(Bh + bpx * 32 + sw0) = v0;                     \
        *(f16x8*)(Bh + bpx * 32 + sw1) = v1;                     \
    } while (0)

    LOADB(0);
    AGLOAD(0);
    CVTB();          // B tile 0 -> LDS, stats for tile 0
    LOADB(32);       // prefetch tile 1 regs

#pragma unroll 1
    for (int kc = 0; kc < 512; kc += 32) {
        __syncthreads();   // A(kc) + B(kc) visible (barrier drains vmcnt/lgkm)
        f16x8 ah[4], al[4], bh[4];
#pragma unroll
        for (int i = 0; i < 4; ++i) {
            const int ra = (wm + i * 16 + lr) * 32 + swz;
            ah[i] = *(const f16x8*)(Ah + ra);
            al[i] = *(const f16x8*)(Al + ra);
            const int rb = (wn + i * 16 + lr) * 32 + swz;
            bh[i] = *(const f16x8*)(Bh + rb);
        }
        __syncthreads();   // frag reads done; LDS free to overwrite
        if (kc + 32 < 512) {
            AGLOAD(kc + 32);
            CVTB();                          // B(kc+32) from regs -> LDS + stats
            if (kc + 64 < 512) LOADB(kc + 64);
        }
#pragma unroll
        for (int i = 0; i < 4; ++i)
#pragma unroll
            for (int j = 0; j < 4; ++j) {
                acc[i][j] = __builtin_amdgcn_mfma_f32_16x16x32_f16(ah[i], bh[j], acc[i][j], 0, 0, 0);
                acc[i][j] = __builtin_amdgcn_mfma_f32_16x16x32_f16(al[i], bh[j], acc[i][j], 0, 0, 0);
            }
    }
#undef AGLOAD
#undef LOADB
#undef CVTB

    // ---- in-block LN stats reduce (reuse A LDS) ----
    __syncthreads();
    float* rs1 = (float*)Ah;          // [2][128]
    float* rs2 = rs1 + 256;           // [2][128]
    float* mnS = rs2 + 256;           // [128]
    float* rsS = mnS + 128;           // [128]
    rs1[bslot * 128 + bpx] = s1t;
    rs2[bslot * 128 + bpx] = s2t;
    __syncthreads();
    if (tid < 128) {
        const float S1 = rs1[tid] + rs1[tid + 128];
        const float S2 = rs2[tid] + rs2[tid + 128];
        const float m = S1 * (1.f / 512.f);
        float var = S2 * (1.f / 512.f) - m * m;
        var = fmaxf(var, 0.f);
        mnS[tid] = m;
        rsS[tid] = rsqrtf(var + LN_EPS);
    }
    __syncthreads();

    // ---- epilogue: qkv fp16 = rstd*(acc/64 - mean*s[o]) ----
    float mn[4], rs[4];
#pragma unroll
    for (int j = 0; j < 4; ++j) {
        const int px = wn + j * 16 + lr;
        mn[j] = mnS[px]; rs[j] = rsS[px];
    }
#pragma unroll
    for (int i = 0; i < 4; ++i)
#pragma unroll
        for (int r = 0; r < 4; ++r) {
            const int o = om + wm + i * 16 + kg * 4 + r;
            const float so = sv[o];
            h16* dst = qout + ((size_t)bb * OC3 + o) * HWN;
#pragma unroll
            for (int j = 0; j < 4; ++j) {
                const int hw = hw0 + wn + j * 16 + lr;
                dst[hw] = (h16)(rs[j] * (acc[i][j][r] * (1.f / 64.f) - mn[j] * so));
            }
        }
}

// ---------------------------------------------------------------------------
// per-row (over n=4096) max and 1/sum(exp) for k (fp16 input, one wave/row)
__global__ __launch_bounds__(256) void k_stats(const h16* __restrict__ qkv16,
                                               float* __restrict__ kmax,
                                               float* __restrict__ ksc) {
    const int row = blockIdx.x * 4 + (threadIdx.x >> 6);
    const int bh = row >> 6, r = row & 63;
    const int b = bh >> 3, h = bh & 7;
    const h16* rp = qkv16 + ((size_t)b * OC3 + CCH + h * 64 + r) * HWN;
    const int lane = threadIdx.x & 63;
    f16x8 kv[8];
#pragma unroll
    for (int j = 0; j < 8; ++j) kv[j] = *(const f16x8*)(rp + lane * 8 + j * 512);
    float mx = -1e30f;
#pragma unroll
    for (int j = 0; j < 8; ++j)
#pragma unroll
        for (int u = 0; u < 8; ++u) mx = fmaxf(mx, (float)kv[j][u]);
    mx = waveReduceMax(mx);
    float sum = 0.f;
#pragma unroll
    for (int j = 0; j < 8; ++j)
#pragma unroll
        for (int u = 0; u < 8; ++u) sum += __expf((float)kv[j][u] - mx);
    sum = waveReduceSum(sum);
    if (lane == 0) {
        kmax[row] = mx;
        ksc[row]  = 1.0f / sum;
    }
}

// ---------------------------------------------------------------------------
// partial context over an n-chunk of 1024: ctp = sum_n ktilde[d,n]*V[e,n]
__global__ __launch_bounds__(256) void ctx_partial(const h16* __restrict__ qkv16,
                                                   const float* __restrict__ kmax,
                                                   const float* __restrict__ ksc,
                                                   float* __restrict__ ctp) {
    __shared__ float kt[64][68];
    __shared__ float vt[64][68];
    __shared__ float kmx[64], kss[64];

    const int bh = blockIdx.y, ci = blockIdx.x;
    const int b = bh >> 3, h = bh & 7;
    const h16* kb = qkv16 + ((size_t)b * OC3 + CCH  + h * 64) * HWN;
    const h16* vb = qkv16 + ((size_t)b * OC3 + 1024 + h * 64) * HWN;
    const int tid = threadIdx.x;
    if (tid < 64) { kmx[tid] = kmax[bh * 64 + tid]; kss[tid] = ksc[bh * 64 + tid]; }

    const int d  = tid >> 2;
    const int td = tid & 15, te = tid >> 4;
    float acc[4][4];
#pragma unroll
    for (int i = 0; i < 4; ++i)
#pragma unroll
        for (int j = 0; j < 4; ++j) acc[i][j] = 0.f;

    for (int t = 0; t < 16; ++t) {
        const int n0 = ci * 1024 + t * 64;
        __syncthreads();
        const float m = kmx[d], sc = kss[d];
#pragma unroll
        for (int jj = 0; jj < 2; ++jj) {
            const int nn = (tid & 3) * 8 + jj * 32;
            const f16x8 kv = *(const f16x8*)(kb + (size_t)d * HWN + n0 + nn);
            const f16x8 vv = *(const f16x8*)(vb + (size_t)d * HWN + n0 + nn);
#pragma unroll
            for (int u = 0; u < 8; ++u) {
                kt[nn + u][d] = __expf((float)kv[u] - m) * sc;
                vt[nn + u][d] = (float)vv[u];
            }
        }
        __syncthreads();
#pragma unroll
        for (int nn = 0; nn < 64; ++nn) {
            float kf[4], vf[4];
            *(float4*)kf = *(const float4*)&kt[nn][td * 4];
            *(float4*)vf = *(const float4*)&vt[nn][te * 4];
#pragma unroll
            for (int i = 0; i < 4; ++i)
#pragma unroll
                for (int j = 0; j < 4; ++j)
                    acc[i][j] = fmaf(kf[i], vf[j], acc[i][j]);
        }
    }
    float* dst = ctp + ((size_t)bh * 4 + ci) * 4096;
#pragma unroll
    for (int i = 0; i < 4; ++i) {
        const float4 o4 = make_float4(acc[i][0], acc[i][1], acc[i][2], acc[i][3]);
        *(float4*)(dst + (td * 4 + i) * 64 + te * 4) = o4;
    }
}

__global__ __launch_bounds__(256) void ctx_reduce(const float* __restrict__ ctp,
                                                  float* __restrict__ ct) {
    const int bh = blockIdx.x;
    const int tid = threadIdx.x;
    const float* src = ctp + (size_t)bh * 4 * 4096;
    float* dst = ct + (size_t)bh * 4096;
    for (int e4 = tid * 4; e4 < 4096; e4 += 1024) {
        float4 sum = make_float4(0.f, 0.f, 0.f, 0.f);
#pragma unroll
        for (int ci = 0; ci < 4; ++ci) {
            const float4 v = *(const float4*)(src + (size_t)ci * 4096 + e4);
            sum.x += v.x; sum.y += v.y; sum.z += v.z; sum.w += v.w;
        }
        *(float4*)(dst + e4) = sum;
    }
}

// ---------------------------------------------------------------------------
// q-softmax(d) * (512*SCALE), out'[e,n] = sum_d ct[d,e]*qtilde[d,n];
// writes at = fp16, TRANSPOSED to [b*4096+n][512] (in ws)
__global__ __launch_bounds__(256) void attn_out(const h16* __restrict__ qkv16,
                                                const float* __restrict__ ct,
                                                h16* __restrict__ at) {
    __shared__ float cts[64][68];
    __shared__ float qt[64][68];

    const int bh = blockIdx.y, ci = blockIdx.x;
    const int b = bh >> 3, h = bh & 7;
    const h16* qb = qkv16 + ((size_t)b * OC3 + h * 64) * HWN;
    const int tid = threadIdx.x;

    for (int i4 = tid * 4; i4 < 4096; i4 += 1024) {
        const float4 v = *(const float4*)(ct + (size_t)bh * 4096 + i4);
        *(float4*)&cts[i4 >> 6][i4 & 63] = v;
    }

    const int d  = tid >> 2;
    const int te = tid & 15, tn = tid >> 4;
    const int rn = tid >> 2, d0q = (tid & 3) * 16;

    for (int t = 0; t < 8; ++t) {
        const int n0 = ci * 512 + t * 64;
        __syncthreads();
#pragma unroll
        for (int jj = 0; jj < 2; ++jj) {
            const int nn = (tid & 3) * 8 + jj * 32;
            const f16x8 qv = *(const f16x8*)(qb + (size_t)d * HWN + n0 + nn);
#pragma unroll
            for (int u = 0; u < 8; ++u) qt[nn + u][d] = (float)qv[u];
        }
        __syncthreads();
        {   // wave-parallel softmax over d (row rn, 16 cols per lane)
            float mx = -1e30f;
#pragma unroll
            for (int dd = 0; dd < 16; ++dd) mx = fmaxf(mx, qt[rn][d0q + dd]);
            mx = fmaxf(mx, __shfl_xor(mx, 1));
            mx = fmaxf(mx, __shfl_xor(mx, 2));
            float sm = 0.f;
#pragma unroll
            for (int dd = 0; dd < 16; ++dd) sm += __expf(qt[rn][d0q + dd] - mx);
            sm += __shfl_xor(sm, 1);
            sm += __shfl_xor(sm, 2);
            const float sc = 512.f * QSCALE / sm;
#pragma unroll
            for (int dd = 0; dd < 16; ++dd)
                qt[rn][d0q + dd] = __expf(qt[rn][d0q + dd] - mx) * sc;
        }
        __syncthreads();
        float acc[4][4];
#pragma unroll
        for (int i = 0; i < 4; ++i)
#pragma unroll
            for (int j = 0; j < 4; ++j) acc[i][j] = 0.f;
#pragma unroll
        for (int dd = 0; dd < 64; ++dd) {
            float cv[4];
            *(float4*)cv = *(const float4*)&cts[dd][te * 4];
            const float q0 = qt[tn * 4 + 0][dd];
            const float q1 = qt[tn * 4 + 1][dd];
            const float q2 = qt[tn * 4 + 2][dd];
            const float q3 = qt[tn * 4 + 3][dd];
#pragma unroll
            for (int i = 0; i < 4; ++i) {
                acc[i][0] = fmaf(cv[i], q0, acc[i][0]);
                acc[i][1] = fmaf(cv[i], q1, acc[i][1]);
                acc[i][2] = fmaf(cv[i], q2, acc[i][2]);
                acc[i][3] = fmaf(cv[i], q3, acc[i][3]);
            }
        }
        __syncthreads();
#pragma unroll
        for (int i = 0; i < 4; ++i)
#pragma unroll
            for (int j = 0; j < 4; ++j)
                qt[tn * 4 + j][te * 4 + i] = acc[i][j];
        __syncthreads();
        {
            const int px = tid >> 2, e0 = (tid & 3) * 16;
            f16x8 vh0, vh1;
#pragma unroll
            for (int u = 0; u < 8; ++u) {
                vh0[u] = (h16)qt[px][e0 + u];
                vh1[u] = (h16)qt[px][e0 + 8 + u];
            }
            const size_t o = ((size_t)b * HWN + n0 + px) * CCH + h * 64 + e0;
            *(f16x8*)(at + o)     = vh0;
            *(f16x8*)(at + o + 8) = vh1;
        }
    }
}

// ---------------------------------------------------------------------------
// Fused out-GEMM + channel LN + residual. split-2: (wo_hi,at),(wo_lo,at).
// block = 512 channels x 128 pixels, 8 waves; virtual K = 1024 (32 steps).
__global__ __launch_bounds__(512) void out_fused(const h16* __restrict__ wo_hi,
                                                 const h16* __restrict__ wo_lo,
                                                 const h16* __restrict__ at,
                                                 const float* __restrict__ b_out,
                                                 const float* __restrict__ g_out,
                                                 const float* __restrict__ x,
                                                 float* __restrict__ out) {
    __shared__ __align__(16) h16 Alds[512 * 32];   // 32 KB
    __shared__ __align__(16) h16 Blds[128 * 32];   // 8 KB
    __shared__ float red1[4][128], red2[4][128];
    __shared__ float mnS[128], rsS[128];

    const int tid = threadIdx.x;
    const int p0 = blockIdx.x * 128;
    const int b = p0 >> 12, hw0 = p0 & 4095;

    const int trow = tid >> 2;
    const int skh  = ((tid & 3) ^ (trow & 3)) * 8;
    const size_t aoff = (size_t)trow * CCH + skh;
    const size_t boff = (size_t)p0 * CCH + aoff;
    const int wofs = (tid >> 6) * 512;

    const int wv = tid >> 6;
    const int wm = (wv >> 1) * 128, wn = (wv & 1) * 64;
    const int lane = tid & 63;
    const int lr = lane & 15, kg = lane >> 4;
    const int swz = (kg ^ (lr & 3)) * 8;

    f32x4 acc[8][4];
#pragma unroll
    for (int i = 0; i < 8; ++i)
#pragma unroll
        for (int j = 0; j < 4; ++j) acc[i][j] = {0.f, 0.f, 0.f, 0.f};

#define STAGEF(S)                                                       \
    do {                                                                \
        const int kc_ = ((S) & 15) * 32;                                \
        const h16* As_ = ((S) < 16) ? wo_hi : wo_lo;                    \
        gl_lds16(As_ + aoff + kc_,               Alds + wofs);          \
        gl_lds16(As_ + aoff + kc_ + 128 * CCH,   Alds + 4096 + wofs);   \
        gl_lds16(As_ + aoff + kc_ + 256 * CCH,   Alds + 8192 + wofs);   \
        gl_lds16(As_ + aoff + kc_ + 384 * CCH,   Alds + 12288 + wofs);  \
        gl_lds16(at + boff + kc_,                Blds + wofs);          \
    } while (0)

    STAGEF(0);
#pragma unroll 1
    for (int s = 0; s < 32; ++s) {
        __syncthreads();
        f16x8 af[8], bf[4];
#pragma unroll
        for (int i = 0; i < 8; ++i)
            af[i] = *(const f16x8*)(Alds + (wm + i * 16 + lr) * 32 + swz);
#pragma unroll
        for (int j = 0; j < 4; ++j)
            bf[j] = *(const f16x8*)(Blds + (wn + j * 16 + lr) * 32 + swz);
        __syncthreads();
        if (s < 31) STAGEF(s + 1);
#pragma unroll
        for (int i = 0; i < 8; ++i)
#pragma unroll
            for (int j = 0; j < 4; ++j)
                acc[i][j] = __builtin_amdgcn_mfma_f32_16x16x32_f16(af[i], bf[j], acc[i][j], 0, 0, 0);
    }
#undef STAGEF

    // ---- epilogue: y = acc*2^-27 + bias ----
#pragma unroll
    for (int i = 0; i < 8; ++i) {
        const int o = wm + i * 16 + kg * 4;
        const float4 bb = *(const float4*)(b_out + o);
#pragma unroll
        for (int j = 0; j < 4; ++j) {
            acc[i][j][0] = acc[i][j][0] * (1.f / 134217728.f) + bb.x;
            acc[i][j][1] = acc[i][j][1] * (1.f / 134217728.f) + bb.y;
            acc[i][j][2] = acc[i][j][2] * (1.f / 134217728.f) + bb.z;
            acc[i][j][3] = acc[i][j][3] * (1.f / 134217728.f) + bb.w;
        }
    }
    float s1[4], s2[4];
#pragma unroll
    for (int j = 0; j < 4; ++j) {
        s1[j] = 0.f; s2[j] = 0.f;
#pragma unroll
        for (int i = 0; i < 8; ++i)
#pragma unroll
            for (int r = 0; r < 4; ++r) {
                const float v = acc[i][j][r];
                s1[j] += v; s2[j] += v * v;
            }
        s1[j] += __shfl_xor(s1[j], 16); s1[j] += __shfl_xor(s1[j], 32);
        s2[j] += __shfl_xor(s2[j], 16); s2[j] += __shfl_xor(s2[j], 32);
    }
    if (kg == 0) {
#pragma unroll
        for (int j = 0; j < 4; ++j) {
            red1[wv >> 1][wn + j * 16 + lr] = s1[j];
            red2[wv >> 1][wn + j * 16 + lr] = s2[j];
        }
    }
    __syncthreads();
    if (tid < 128) {
        const float S1 = red1[0][tid] + red1[1][tid] + red1[2][tid] + red1[3][tid];
        const float S2 = red2[0][tid] + red2[1][tid] + red2[2][tid] + red2[3][tid];
        const float m = S1 * (1.f / 512.f);
        float var = S2 * (1.f / 512.f) - m * m;
        var = fmaxf(var, 0.f);
        mnS[tid] = m;
        rsS[tid] = rsqrtf(var + LN_EPS);
    }
    __syncthreads();
    float mj[4], rj[4];
#pragma unroll
    for (int j = 0; j < 4; ++j) {
        const int px = wn + j * 16 + lr;
        mj[j] = mnS[px]; rj[j] = rsS[px];
    }
#pragma unroll
    for (int i = 0; i < 8; ++i) {
        const int o = wm + i * 16 + kg * 4;
        const float4 gg = *(const float4*)(g_out + o);
#pragma unroll
        for (int r = 0; r < 4; ++r) {
            const float g = (r == 0) ? gg.x : (r == 1) ? gg.y : (r == 2) ? gg.z : gg.w;
            const float* xr = x + ((size_t)b * CCH + o + r) * HWN + hw0 + wn;
            float* dr = out + ((size_t)b * CCH + o + r) * HWN + hw0 + wn;
#pragma unroll
            for (int j = 0; j < 4; ++j) {
                const int c = j * 16 + lr;
                dr[c] = (acc[i][j][r] - mj[j]) * rj[j] * g + xr[c];
            }
        }
    }
}

// ---------------------------------------------------------------------------
extern "C" void kernel_launch(void* const* d_in, const int* in_sizes, int n_in,
                              void* d_out, int out_size, void* d_ws, size_t ws_size,
                              hipStream_t stream) {
    (void)in_sizes; (void)n_in; (void)out_size;
    const float* x     = (const float*)d_in[0];
    const float* w_qkv = (const float*)d_in[1];
    const float* w_out = (const float*)d_in[2];
    const float* b_out = (const float*)d_in[3];
    const float* g_out = (const float*)d_in[4];
    const float* g_ln  = (const float*)d_in[5];
    float* out = (float*)d_out;
    float* ws  = (float*)d_ws;

    float* s    = ws;                       // 1536
    float* kmax = s + OC3;                  // 8192
    float* ksc  = kmax + 8192;              // 8192
    float* ct   = ksc + 8192;               // 524288
    float* ctp  = ct + 524288;              // 2097152
    h16*  wg_hi = (h16*)(ctp + 2097152);    // 786432 halfs
    h16*  wg_lo = wg_hi + 786432;
    h16*  wo_hi = wg_lo + 786432;           // 262144 halfs
    h16*  wo_lo = wo_hi + 262144;
    h16*  qkv16 = wo_lo + 262144;           // 100663296 halfs (fp16 q,k,v)
    h16*  at    = qkv16 + 100663296;        // 33554432 halfs (attn out, transposed)

    const size_t need = 70796800ULL * 4ULL;   // ~283.2 MB
    if (ws_size < need) return;

    prep_w     <<<2048, 64, 0, stream>>>(w_qkv, g_ln, w_out,
                                         wg_hi, wg_lo, s, wo_hi, wo_lo);
    qkv_gemm   <<<dim3(12, 512), 256, 0, stream>>>(wg_hi, wg_lo, x, s, qkv16);
    k_stats    <<<2048, 256, 0, stream>>>(qkv16, kmax, ksc);
    ctx_partial<<<dim3(4, 128), 256, 0, stream>>>(qkv16, kmax, ksc, ctp);
    ctx_reduce <<<128, 256, 0, stream>>>(ctp, ct);
    attn_out   <<<dim3(8, 128), 256, 0, stream>>>(qkv16, ct, at);
    out_fused  <<<512, 512, 0, stream>>>(wo_hi, wo_lo, at,
                                         b_out, g_out, x, out);
}

// Round 8
// 581.066 us; speedup vs baseline: 1.3055x; 1.3055x over previous
//
#include <hip/hip_runtime.h>
#include <math.h>

#define CCH    512
#define HWN    4096
#define NPIX   65536
#define OC3    1536
#define QSCALE 0.125f
#define LN_EPS 1e-5f

typedef _Float16 h16;
typedef h16  f16x8 __attribute__((ext_vector_type(8)));
typedef float f32x4 __attribute__((ext_vector_type(4)));

__device__ __forceinline__ float waveReduceSum(float v) {
#pragma unroll
    for (int off = 32; off; off >>= 1) v += __shfl_xor(v, off);
    return v;
}
__device__ __forceinline__ float waveReduceMax(float v) {
#pragma unroll
    for (int off = 32; off; off >>= 1) v = fmaxf(v, __shfl_xor(v, off));
    return v;
}

__device__ __forceinline__ void gl_lds16(const void* g, void* l) {
    __builtin_amdgcn_global_load_lds((const __attribute__((address_space(1))) void*)g,
                                     (__attribute__((address_space(3))) void*)l, 16, 0, 0);
}

// ---------------------------------------------------------------------------
// merged weight prep: o<1536 -> wg (w_qkv*g_ln, x64, hi/lo) + row-sum s;
//                     o>=1536 -> wo (w_out, x64, hi/lo)
__global__ __launch_bounds__(64) void prep_w(const float* __restrict__ w_qkv,
                                             const float* __restrict__ g_ln,
                                             const float* __restrict__ w_out,
                                             h16* __restrict__ wg_h, h16* __restrict__ wg_l,
                                             float* __restrict__ s,
                                             h16* __restrict__ wo_h, h16* __restrict__ wo_l) {
    const int o = blockIdx.x, lane = threadIdx.x;
    if (o < OC3) {
        float sum = 0.f;
#pragma unroll
        for (int j = 0; j < 8; ++j) {
            const int c = lane + j * 64;
            const float w = w_qkv[(size_t)o * CCH + c] * g_ln[c];
            const float ws = w * 64.f;
            const h16 hi = (h16)ws;
            wg_h[(size_t)o * CCH + c] = hi;
            wg_l[(size_t)o * CCH + c] = (h16)(ws - (float)hi);
            sum += w;
        }
        sum = waveReduceSum(sum);
        if (lane == 0) s[o] = sum;
    } else {
        const int r = o - OC3;
#pragma unroll
        for (int j = 0; j < 8; ++j) {
            const int c = lane + j * 64;
            const float ws = w_out[(size_t)r * CCH + c] * 64.f;
            const h16 hi = (h16)ws;
            wo_h[(size_t)r * CCH + c] = hi;
            wo_l[(size_t)r * CCH + c] = (h16)(ws - (float)hi);
        }
    }
}

// ---------------------------------------------------------------------------
// fp32 [16][512][4096] -> transposed fp16 [16][4096][512]
// + per-(channel-block, pixel) LN partial sums (deterministic 2-stage stats)
__global__ __launch_bounds__(256) void transpose_cvt(const float* __restrict__ src,
                                                     h16* __restrict__ dhi,
                                                     float* __restrict__ psum,
                                                     float* __restrict__ psq) {
    __shared__ float tile[64][65];
    __shared__ float ps1[4][64], ps2[4][64];
    const int b = blockIdx.z, c0 = blockIdx.y * 64, p0 = blockIdx.x * 64;
    const int t = threadIdx.x;
    const float* sb = src + ((size_t)b * CCH + c0) * HWN + p0;
    const int rc = t >> 4, cc4 = (t & 15) * 4;
#pragma unroll
    for (int ps = 0; ps < 4; ++ps) {
        const float4 v = *(const float4*)(sb + (size_t)(rc + ps * 16) * HWN + cc4);
        tile[rc + ps * 16][cc4 + 0] = v.x;
        tile[rc + ps * 16][cc4 + 1] = v.y;
        tile[rc + ps * 16][cc4 + 2] = v.z;
        tile[rc + ps * 16][cc4 + 3] = v.w;
    }
    __syncthreads();
    {
        const int q = t >> 6, px = t & 63;
        float s1 = 0.f, s2 = 0.f;
#pragma unroll
        for (int c = q * 16; c < q * 16 + 16; ++c) {
            const float v = tile[c][px];
            s1 += v; s2 += v * v;
        }
        ps1[q][px] = s1; ps2[q][px] = s2;
    }
    const int pr0 = t >> 3, cs = (t & 7) * 8;
#pragma unroll
    for (int ps = 0; ps < 2; ++ps) {
        const int pr = pr0 + ps * 32;
        f16x8 vh;
#pragma unroll
        for (int q = 0; q < 8; ++q) vh[q] = (h16)tile[cs + q][pr];
        const size_t o = ((size_t)b * HWN + p0 + pr) * CCH + c0 + cs;
        *(f16x8*)(dhi + o) = vh;
    }
    __syncthreads();
    if (t < 64) {
        const float s1 = ps1[0][t] + ps1[1][t] + ps1[2][t] + ps1[3][t];
        const float s2 = ps2[0][t] + ps2[1][t] + ps2[2][t] + ps2[3][t];
        const size_t gp = (size_t)b * HWN + p0 + t;
        psum[(size_t)(c0 >> 6) * NPIX + gp] = s1;
        psq [(size_t)(c0 >> 6) * NPIX + gp] = s2;
    }
}

__global__ __launch_bounds__(256) void ln_finish(const float* __restrict__ psum,
                                                 const float* __restrict__ psq,
                                                 float* __restrict__ mean,
                                                 float* __restrict__ rstd) {
    const int p = blockIdx.x * 256 + threadIdx.x;
    float s1 = 0.f, s2 = 0.f;
#pragma unroll
    for (int cb = 0; cb < 8; ++cb) {
        s1 += psum[(size_t)cb * NPIX + p];
        s2 += psq [(size_t)cb * NPIX + p];
    }
    const float m = s1 * (1.f / 512.f);
    float var = s2 * (1.f / 512.f) - m * m;
    var = fmaxf(var, 0.f);
    mean[p] = m;
    rstd[p] = rsqrtf(var + LN_EPS);
}

// ---------------------------------------------------------------------------
// QKV GEMM: 128x128 MFMA, fp16 split-2 (A hi/lo x B hi), K=512. A = wg (x64).
// out fp16 = rstd[p]*(acc/64 - mean[p]*s[o]).
__global__ __launch_bounds__(256) void qkv_gemm(const h16* __restrict__ Ahg,
                                                const h16* __restrict__ Alg,
                                                const h16* __restrict__ Bhg,
                                                const float* __restrict__ sv,
                                                const float* __restrict__ mean,
                                                const float* __restrict__ rstd,
                                                h16* __restrict__ qout) {
    __shared__ __align__(16) h16 Ah[4096], Al[4096], Bh[4096];
    const int tid = threadIdx.x;
    const int om = blockIdx.x * 128;
    const int by0 = blockIdx.y;
    const int by  = (by0 & 7) * 64 + (by0 >> 3);   // bijective XCD chunking (512%8==0)
    const int p0  = by * 128;

    const int srow = tid >> 2;
    const int skh  = ((tid & 3) ^ (srow & 3)) * 8;
    const size_t a0 = (size_t)(om + srow) * CCH + skh;
    const size_t b0 = (size_t)(p0 + srow) * CCH + skh;
    const int wofs = (tid >> 6) * 512;

    const int lane = tid & 63;
    const int wv = tid >> 6;
    const int wm = (wv >> 1) * 64, wn = (wv & 1) * 64;
    const int lr = lane & 15, kg = lane >> 4;
    const int swz = (kg ^ (lr & 3)) * 8;

    f32x4 acc[4][4];
#pragma unroll
    for (int i = 0; i < 4; ++i)
#pragma unroll
        for (int j = 0; j < 4; ++j) acc[i][j] = {0.f, 0.f, 0.f, 0.f};

#define STAGE(KC)                                               \
    do {                                                        \
        gl_lds16(Ahg + a0 + (KC), Ah + wofs);                   \
        gl_lds16(Ahg + a0 + (KC) + 64 * CCH, Ah + 2048 + wofs); \
        gl_lds16(Alg + a0 + (KC), Al + wofs);                   \
        gl_lds16(Alg + a0 + (KC) + 64 * CCH, Al + 2048 + wofs); \
        gl_lds16(Bhg + b0 + (KC), Bh + wofs);                   \
        gl_lds16(Bhg + b0 + (KC) + 64 * CCH, Bh + 2048 + wofs); \
    } while (0)

    STAGE(0);
#pragma unroll 1
    for (int kc = 0; kc < 512; kc += 32) {
        __syncthreads();
        f16x8 ah[4], al[4], bh[4];
#pragma unroll
        for (int i = 0; i < 4; ++i) {
            const int ra = (wm + i * 16 + lr) * 32 + swz;
            ah[i] = *(const f16x8*)(Ah + ra);
            al[i] = *(const f16x8*)(Al + ra);
            const int rb = (wn + i * 16 + lr) * 32 + swz;
            bh[i] = *(const f16x8*)(Bh + rb);
        }
        __syncthreads();
        if (kc + 32 < 512) STAGE(kc + 32);
#pragma unroll
        for (int i = 0; i < 4; ++i)
#pragma unroll
            for (int j = 0; j < 4; ++j) {
                acc[i][j] = __builtin_amdgcn_mfma_f32_16x16x32_f16(ah[i], bh[j], acc[i][j], 0, 0, 0);
                acc[i][j] = __builtin_amdgcn_mfma_f32_16x16x32_f16(al[i], bh[j], acc[i][j], 0, 0, 0);
            }
    }
#undef STAGE

    const int b = p0 >> 12, hw0 = p0 & 4095;
    float mn[4], rs[4];
#pragma unroll
    for (int j = 0; j < 4; ++j) {
        const int p = p0 + wn + j * 16 + lr;
        mn[j] = mean[p]; rs[j] = rstd[p];
    }
#pragma unroll
    for (int i = 0; i < 4; ++i)
#pragma unroll
        for (int r = 0; r < 4; ++r) {
            const int o = om + wm + i * 16 + kg * 4 + r;
            const float so = sv[o];
            h16* dst = qout + ((size_t)b * OC3 + o) * HWN;
#pragma unroll
            for (int j = 0; j < 4; ++j) {
                const int hw = hw0 + wn + j * 16 + lr;
                dst[hw] = (h16)(rs[j] * (acc[i][j][r] * (1.f / 64.f) - mn[j] * so));
            }
        }
}

// ---------------------------------------------------------------------------
// per-row (over n=4096) max and 1/sum(exp) for k (fp16 input, one wave/row)
__global__ __launch_bounds__(256) void k_stats(const h16* __restrict__ qkv16,
                                               float* __restrict__ kmax,
                                               float* __restrict__ ksc) {
    const int row = blockIdx.x * 4 + (threadIdx.x >> 6);
    const int bh = row >> 6, r = row & 63;
    const int b = bh >> 3, h = bh & 7;
    const h16* rp = qkv16 + ((size_t)b * OC3 + CCH + h * 64 + r) * HWN;
    const int lane = threadIdx.x & 63;
    f16x8 kv[8];
#pragma unroll
    for (int j = 0; j < 8; ++j) kv[j] = *(const f16x8*)(rp + lane * 8 + j * 512);
    float mx = -1e30f;
#pragma unroll
    for (int j = 0; j < 8; ++j)
#pragma unroll
        for (int u = 0; u < 8; ++u) mx = fmaxf(mx, (float)kv[j][u]);
    mx = waveReduceMax(mx);
    float sum = 0.f;
#pragma unroll
    for (int j = 0; j < 8; ++j)
#pragma unroll
        for (int u = 0; u < 8; ++u) sum += __expf((float)kv[j][u] - mx);
    sum = waveReduceSum(sum);
    if (lane == 0) {
        kmax[row] = mx;
        ksc[row]  = 1.0f / sum;
    }
}

// ---------------------------------------------------------------------------
// partial context over an n-chunk of 512: ctp = sum_n ktilde[d,n]*V[e,n]
__global__ __launch_bounds__(256) void ctx_partial(const h16* __restrict__ qkv16,
                                                   const float* __restrict__ kmax,
                                                   const float* __restrict__ ksc,
                                                   float* __restrict__ ctp) {
    __shared__ float kt[64][68];
    __shared__ float vt[64][68];
    __shared__ float kmx[64], kss[64];

    const int bh = blockIdx.y, ci = blockIdx.x;
    const int b = bh >> 3, h = bh & 7;
    const h16* kb = qkv16 + ((size_t)b * OC3 + CCH  + h * 64) * HWN;
    const h16* vb = qkv16 + ((size_t)b * OC3 + 1024 + h * 64) * HWN;
    const int tid = threadIdx.x;
    if (tid < 64) { kmx[tid] = kmax[bh * 64 + tid]; kss[tid] = ksc[bh * 64 + tid]; }

    const int d  = tid >> 2;
    const int td = tid & 15, te = tid >> 4;
    float acc[4][4];
#pragma unroll
    for (int i = 0; i < 4; ++i)
#pragma unroll
        for (int j = 0; j < 4; ++j) acc[i][j] = 0.f;

    for (int t = 0; t < 8; ++t) {
        const int n0 = ci * 512 + t * 64;
        __syncthreads();
        const float m = kmx[d], sc = kss[d];
#pragma unroll
        for (int jj = 0; jj < 2; ++jj) {
            const int nn = (tid & 3) * 8 + jj * 32;
            const f16x8 kv = *(const f16x8*)(kb + (size_t)d * HWN + n0 + nn);
            const f16x8 vv = *(const f16x8*)(vb + (size_t)d * HWN + n0 + nn);
#pragma unroll
            for (int u = 0; u < 8; ++u) {
                kt[nn + u][d] = __expf((float)kv[u] - m) * sc;
                vt[nn + u][d] = (float)vv[u];
            }
        }
        __syncthreads();
#pragma unroll
        for (int nn = 0; nn < 64; ++nn) {
            float kf[4], vf[4];
            *(float4*)kf = *(const float4*)&kt[nn][td * 4];
            *(float4*)vf = *(const float4*)&vt[nn][te * 4];
#pragma unroll
            for (int i = 0; i < 4; ++i)
#pragma unroll
                for (int j = 0; j < 4; ++j)
                    acc[i][j] = fmaf(kf[i], vf[j], acc[i][j]);
        }
    }
    float* dst = ctp + ((size_t)bh * 8 + ci) * 4096;
#pragma unroll
    for (int i = 0; i < 4; ++i) {
        const float4 o4 = make_float4(acc[i][0], acc[i][1], acc[i][2], acc[i][3]);
        *(float4*)(dst + (td * 4 + i) * 64 + te * 4) = o4;
    }
}

__global__ __launch_bounds__(256) void ctx_reduce(const float* __restrict__ ctp,
                                                  float* __restrict__ ct) {
    const int bh = blockIdx.x;
    const int tid = threadIdx.x;
    const float* src = ctp + (size_t)bh * 8 * 4096;
    float* dst = ct + (size_t)bh * 4096;
    for (int e4 = tid * 4; e4 < 4096; e4 += 1024) {
        float4 sum = make_float4(0.f, 0.f, 0.f, 0.f);
#pragma unroll
        for (int ci = 0; ci < 8; ++ci) {
            const float4 v = *(const float4*)(src + (size_t)ci * 4096 + e4);
            sum.x += v.x; sum.y += v.y; sum.z += v.z; sum.w += v.w;
        }
        *(float4*)(dst + e4) = sum;
    }
}

// ---------------------------------------------------------------------------
// q-softmax(d) * (512*SCALE), out'[e,n] = sum_d ct[d,e]*qtilde[d,n];
// writes at = fp16, TRANSPOSED to [b*4096+n][512] (in ws).
// Softmax wave-parallel: 4 lanes per row via shfl.
__global__ __launch_bounds__(256) void attn_out(const h16* __restrict__ qkv16,
                                                const float* __restrict__ ct,
                                                h16* __restrict__ at) {
    __shared__ float cts[64][68];
    __shared__ float qt[64][68];

    const int bh = blockIdx.y, ci = blockIdx.x;
    const int b = bh >> 3, h = bh & 7;
    const h16* qb = qkv16 + ((size_t)b * OC3 + h * 64) * HWN;
    const int tid = threadIdx.x;

    for (int i4 = tid * 4; i4 < 4096; i4 += 1024) {
        const float4 v = *(const float4*)(ct + (size_t)bh * 4096 + i4);
        *(float4*)&cts[i4 >> 6][i4 & 63] = v;
    }

    const int d  = tid >> 2;
    const int te = tid & 15, tn = tid >> 4;
    const int rn = tid >> 2, d0q = (tid & 3) * 16;

    for (int t = 0; t < 8; ++t) {
        const int n0 = ci * 512 + t * 64;
        __syncthreads();
#pragma unroll
        for (int jj = 0; jj < 2; ++jj) {
            const int nn = (tid & 3) * 8 + jj * 32;
            const f16x8 qv = *(const f16x8*)(qb + (size_t)d * HWN + n0 + nn);
#pragma unroll
            for (int u = 0; u < 8; ++u) qt[nn + u][d] = (float)qv[u];
        }
        __syncthreads();
        {   // wave-parallel softmax over d (row rn, 16 cols per lane)
            float mx = -1e30f;
#pragma unroll
            for (int dd = 0; dd < 16; ++dd) mx = fmaxf(mx, qt[rn][d0q + dd]);
            mx = fmaxf(mx, __shfl_xor(mx, 1));
            mx = fmaxf(mx, __shfl_xor(mx, 2));
            float sm = 0.f;
#pragma unroll
            for (int dd = 0; dd < 16; ++dd) sm += __expf(qt[rn][d0q + dd] - mx);
            sm += __shfl_xor(sm, 1);
            sm += __shfl_xor(sm, 2);
            const float sc = 512.f * QSCALE / sm;
#pragma unroll
            for (int dd = 0; dd < 16; ++dd)
                qt[rn][d0q + dd] = __expf(qt[rn][d0q + dd] - mx) * sc;
        }
        __syncthreads();
        float acc[4][4];
#pragma unroll
        for (int i = 0; i < 4; ++i)
#pragma unroll
            for (int j = 0; j < 4; ++j) acc[i][j] = 0.f;
#pragma unroll
        for (int dd = 0; dd < 64; ++dd) {
            float cv[4];
            *(float4*)cv = *(const float4*)&cts[dd][te * 4];
            const float q0 = qt[tn * 4 + 0][dd];
            const float q1 = qt[tn * 4 + 1][dd];
            const float q2 = qt[tn * 4 + 2][dd];
            const float q3 = qt[tn * 4 + 3][dd];
#pragma unroll
            for (int i = 0; i < 4; ++i) {
                acc[i][0] = fmaf(cv[i], q0, acc[i][0]);
                acc[i][1] = fmaf(cv[i], q1, acc[i][1]);
                acc[i][2] = fmaf(cv[i], q2, acc[i][2]);
                acc[i][3] = fmaf(cv[i], q3, acc[i][3]);
            }
        }
        __syncthreads();
#pragma unroll
        for (int i = 0; i < 4; ++i)
#pragma unroll
            for (int j = 0; j < 4; ++j)
                qt[tn * 4 + j][te * 4 + i] = acc[i][j];
        __syncthreads();
        {
            const int px = tid >> 2, e0 = (tid & 3) * 16;
            f16x8 vh0, vh1;
#pragma unroll
            for (int u = 0; u < 8; ++u) {
                vh0[u] = (h16)qt[px][e0 + u];
                vh1[u] = (h16)qt[px][e0 + 8 + u];
            }
            const size_t o = ((size_t)b * HWN + n0 + px) * CCH + h * 64 + e0;
            *(f16x8*)(at + o)     = vh0;
            *(f16x8*)(at + o + 8) = vh1;
        }
    }
}

// ---------------------------------------------------------------------------
// Fused out-GEMM + channel LN + residual. split-2: (wo_hi,at),(wo_lo,at).
// block = 512 channels x 128 pixels, 8 waves; virtual K = 1024 (32 steps).
__global__ __launch_bounds__(512) void out_fused(const h16* __restrict__ wo_hi,
                                                 const h16* __restrict__ wo_lo,
                                                 const h16* __restrict__ at,
                                                 const float* __restrict__ b_out,
                                                 const float* __restrict__ g_out,
                                                 const float* __restrict__ x,
                                                 float* __restrict__ out) {
    __shared__ __align__(16) h16 Alds[512 * 32];   // 32 KB
    __shared__ __align__(16) h16 Blds[128 * 32];   // 8 KB
    __shared__ float red1[4][128], red2[4][128];
    __shared__ float mnS[128], rsS[128];

    const int tid = threadIdx.x;
    const int p0 = blockIdx.x * 128;
    const int b = p0 >> 12, hw0 = p0 & 4095;

    const int trow = tid >> 2;
    const int skh  = ((tid & 3) ^ (trow & 3)) * 8;
    const size_t aoff = (size_t)trow * CCH + skh;
    const size_t boff = (size_t)p0 * CCH + aoff;
    const int wofs = (tid >> 6) * 512;

    const int wv = tid >> 6;
    const int wm = (wv >> 1) * 128, wn = (wv & 1) * 64;
    const int lane = tid & 63;
    const int lr = lane & 15, kg = lane >> 4;
    const int swz = (kg ^ (lr & 3)) * 8;

    f32x4 acc[8][4];
#pragma unroll
    for (int i = 0; i < 8; ++i)
#pragma unroll
        for (int j = 0; j < 4; ++j) acc[i][j] = {0.f, 0.f, 0.f, 0.f};

#define STAGEF(S)                                                       \
    do {                                                                \
        const int kc_ = ((S) & 15) * 32;                                \
        const h16* As_ = ((S) < 16) ? wo_hi : wo_lo;                    \
        gl_lds16(As_ + aoff + kc_,               Alds + wofs);          \
        gl_lds16(As_ + aoff + kc_ + 128 * CCH,   Alds + 4096 + wofs);   \
        gl_lds16(As_ + aoff + kc_ + 256 * CCH,   Alds + 8192 + wofs);   \
        gl_lds16(As_ + aoff + kc_ + 384 * CCH,   Alds + 12288 + wofs);  \
        gl_lds16(at + boff + kc_,                Blds + wofs);          \
    } while (0)

    STAGEF(0);
#pragma unroll 1
    for (int s = 0; s < 32; ++s) {
        __syncthreads();
        f16x8 af[8], bf[4];
#pragma unroll
        for (int i = 0; i < 8; ++i)
            af[i] = *(const f16x8*)(Alds + (wm + i * 16 + lr) * 32 + swz);
#pragma unroll
        for (int j = 0; j < 4; ++j)
            bf[j] = *(const f16x8*)(Blds + (wn + j * 16 + lr) * 32 + swz);
        __syncthreads();
        if (s < 31) STAGEF(s + 1);
#pragma unroll
        for (int i = 0; i < 8; ++i)
#pragma unroll
            for (int j = 0; j < 4; ++j)
                acc[i][j] = __builtin_amdgcn_mfma_f32_16x16x32_f16(af[i], bf[j], acc[i][j], 0, 0, 0);
    }
#undef STAGEF

    // ---- epilogue: y = acc*2^-27 + bias ----
#pragma unroll
    for (int i = 0; i < 8; ++i) {
        const int o = wm + i * 16 + kg * 4;
        const float4 bb = *(const float4*)(b_out + o);
#pragma unroll
        for (int j = 0; j < 4; ++j) {
            acc[i][j][0] = acc[i][j][0] * (1.f / 134217728.f) + bb.x;
            acc[i][j][1] = acc[i][j][1] * (1.f / 134217728.f) + bb.y;
            acc[i][j][2] = acc[i][j][2] * (1.f / 134217728.f) + bb.z;
            acc[i][j][3] = acc[i][j][3] * (1.f / 134217728.f) + bb.w;
        }
    }
    float s1[4], s2[4];
#pragma unroll
    for (int j = 0; j < 4; ++j) {
        s1[j] = 0.f; s2[j] = 0.f;
#pragma unroll
        for (int i = 0; i < 8; ++i)
#pragma unroll
            for (int r = 0; r < 4; ++r) {
                const float v = acc[i][j][r];
                s1[j] += v; s2[j] += v * v;
            }
        s1[j] += __shfl_xor(s1[j], 16); s1[j] += __shfl_xor(s1[j], 32);
        s2[j] += __shfl_xor(s2[j], 16); s2[j] += __shfl_xor(s2[j], 32);
    }
    if (kg == 0) {
#pragma unroll
        for (int j = 0; j < 4; ++j) {
            red1[wv >> 1][wn + j * 16 + lr] = s1[j];
            red2[wv >> 1][wn + j * 16 + lr] = s2[j];
        }
    }
    __syncthreads();
    if (tid < 128) {
        const float S1 = red1[0][tid] + red1[1][tid] + red1[2][tid] + red1[3][tid];
        const float S2 = red2[0][tid] + red2[1][tid] + red2[2][tid] + red2[3][tid];
        const float m = S1 * (1.f / 512.f);
        float var = S2 * (1.f / 512.f) - m * m;
        var = fmaxf(var, 0.f);
        mnS[tid] = m;
        rsS[tid] = rsqrtf(var + LN_EPS);
    }
    __syncthreads();
    float mj[4], rj[4];
#pragma unroll
    for (int j = 0; j < 4; ++j) {
        const int px = wn + j * 16 + lr;
        mj[j] = mnS[px]; rj[j] = rsS[px];
    }
#pragma unroll
    for (int i = 0; i < 8; ++i) {
        const int o = wm + i * 16 + kg * 4;
        const float4 gg = *(const float4*)(g_out + o);
#pragma unroll
        for (int r = 0; r < 4; ++r) {
            const float g = (r == 0) ? gg.x : (r == 1) ? gg.y : (r == 2) ? gg.z : gg.w;
            const float* xr = x + ((size_t)b * CCH + o + r) * HWN + hw0 + wn;
            float* dr = out + ((size_t)b * CCH + o + r) * HWN + hw0 + wn;
#pragma unroll
            for (int j = 0; j < 4; ++j) {
                const int c = j * 16 + lr;
                dr[c] = (acc[i][j][r] - mj[j]) * rj[j] * g + xr[c];
            }
        }
    }
}

// ---------------------------------------------------------------------------
extern "C" void kernel_launch(void* const* d_in, const int* in_sizes, int n_in,
                              void* d_out, int out_size, void* d_ws, size_t ws_size,
                              hipStream_t stream) {
    (void)in_sizes; (void)n_in; (void)out_size;
    const float* x     = (const float*)d_in[0];
    const float* w_qkv = (const float*)d_in[1];
    const float* w_out = (const float*)d_in[2];
    const float* b_out = (const float*)d_in[3];
    const float* g_out = (const float*)d_in[4];
    const float* g_ln  = (const float*)d_in[5];
    float* out = (float*)d_out;
    float* ws  = (float*)d_ws;

    float* mean = ws;                       // 65536
    float* rstd = mean + NPIX;              // 65536
    float* s    = rstd + NPIX;              // 1536
    float* kmax = s + OC3;                  // 8192
    float* ksc  = kmax + 8192;              // 8192
    float* ct   = ksc + 8192;               // 524288
    float* ctp  = ct + 524288;              // 4194304 (psum/psq alias: pre-ctx use)
    float* psum = ctp;                      // 524288
    float* psq  = psum + 524288;            // 524288
    h16*  wg_hi = (h16*)(ctp + 4194304);    // 786432 halfs
    h16*  wg_lo = wg_hi + 786432;
    h16*  wo_hi = wg_lo + 786432;           // 262144 halfs
    h16*  wo_lo = wo_hi + 262144;
    h16*  qkv16 = wo_lo + 262144;           // 100663296 halfs (fp16 q,k,v)
    h16*  at    = qkv16 + 100663296;        // 33554432 halfs (attn out, transposed)
    // alias of d_out: xt dead after qkv_gemm (out_fused is sole d_out writer)
    h16*  xt_hi = (h16*)d_out;

    const size_t need = 73025024ULL * 4ULL;   // ~292.1 MB
    if (ws_size < need) return;

    prep_w     <<<2048, 64, 0, stream>>>(w_qkv, g_ln, w_out,
                                         wg_hi, wg_lo, s, wo_hi, wo_lo);
    transpose_cvt<<<dim3(64, 8, 16), 256, 0, stream>>>(x, xt_hi, psum, psq);
    ln_finish  <<<NPIX / 256, 256, 0, stream>>>(psum, psq, mean, rstd);
    qkv_gemm   <<<dim3(12, 512), 256, 0, stream>>>(wg_hi, wg_lo, xt_hi,
                                                   s, mean, rstd, qkv16);
    k_stats    <<<2048, 256, 0, stream>>>(qkv16, kmax, ksc);
    ctx_partial<<<dim3(8, 128), 256, 0, stream>>>(qkv16, kmax, ksc, ctp);
    ctx_reduce <<<128, 256, 0, stream>>>(ctp, ct);
    attn_out   <<<dim3(8, 128), 256, 0, stream>>>(qkv16, ct, at);
    out_fused  <<<512, 512, 0, stream>>>(wo_hi, wo_lo, at,
                                         b_out, g_out, x, out);
}